// Round 2
// baseline (1024.931 us; speedup 1.0000x reference)
//
#include <hip/hip_runtime.h>

#define H_ 128
#define T_ 1024
#define B_ 512
#define I_ 13
#define LOG2E 1.4426950408889634f

typedef _Float16 half8 __attribute__((ext_vector_type(8)));
typedef float float4_ __attribute__((ext_vector_type(4)));

static __device__ __forceinline__ float fast_rcp(float v) {
  return __builtin_amdgcn_rcpf(v);
}
static __device__ __forceinline__ float fast_exp2(float v) {
  return __builtin_amdgcn_exp2f(v);
}
static __device__ __forceinline__ float sigmoid_f(float v) {
  return fast_rcp(1.0f + fast_exp2(-LOG2E * v));
}
static __device__ __forceinline__ float tanh_f(float v) {
  return 2.0f * fast_rcp(1.0f + fast_exp2(-2.0f * LOG2E * v)) - 1.0f;
}

// Workgroup barrier that does NOT drain vmcnt: only LDS ops are ordered.
// Global loads/stores in flight (x prefetch, out stores) keep flying.
static __device__ __forceinline__ void wg_barrier_lds() {
  asm volatile("s_waitcnt lgkmcnt(0)\n\ts_barrier" ::: "memory");
}

// One WG per CU (256 WGs), each owns 2 batch rows for all 1024 steps.
// Weights live in per-wave VGPR MFMA B-fragments (loop-invariant).
// Batch row 0 -> A-tile row 0, batch row 1 -> A-tile row 4, so gate outputs
// land in acc[ti][0] of lanes 0..31 (D row = quad*4 + reg). Wave w owns gate
// tiles {w, w+8, w+16, w+24} == i,f,g,o for cells [16w,16w+16): the cell
// update runs wave-locally on the accumulators -> ONE lgkm-only barrier/step.
__global__ __launch_bounds__(512, 2) void lstm_fused(
    const float* __restrict__ x, const float* __restrict__ Wih,
    const float* __restrict__ Whh, const float* __restrict__ bih,
    const float* __restrict__ bhh, const float* __restrict__ Wfc,
    const float* __restrict__ bfc, float* __restrict__ out)
{
  // Double-buffered A source: [buf][batchrow][col]; cols 0..127 h,
  // 128..140 x, 141..167 zero pad (row stride 168 halfs = 336 B, 16B-aligned)
  __shared__ __align__(16) _Float16 abuf[2][2][168];

  const int tid  = threadIdx.x;
  const int wave = tid >> 6;
  const int lane = tid & 63;
  const int n16  = lane & 15;
  const int quad = lane >> 4;
  const int wgb  = blockIdx.x * 2;

  // ---- W fragments: wave w owns gate tiles {w, w+8, w+16, w+24} ----
  // B layout (16x16x32): lane holds B[k = quad*8 + j][n = n16], j=0..7
  half8 wfrag[4][5];
  float biasv[4];
  #pragma unroll
  for (int ti = 0; ti < 4; ++ti) {
    const int col = (wave + 8 * ti) * 16 + n16;   // gate index 0..511
    biasv[ti] = bih[col] + bhh[col];
    #pragma unroll
    for (int kc = 0; kc < 5; ++kc) {
      half8 f;
      #pragma unroll
      for (int j = 0; j < 8; ++j) {
        const int k = kc * 32 + quad * 8 + j;
        float v = 0.0f;
        if (k < 128)            v = Whh[col * H_ + k];
        else if (k < 128 + I_)  v = Wih[col * I_ + (k - 128)];
        f[j] = (_Float16)v;
      }
      wfrag[ti][kc] = f;
    }
  }
  // fc tile: wave 0 only uses it; k < 128 so only 4 K-chunks
  half8 wfc[4];
  const float biasfc = (n16 < 7) ? bfc[n16] : 0.0f;
  #pragma unroll
  for (int kc = 0; kc < 4; ++kc) {
    half8 f;
    #pragma unroll
    for (int j = 0; j < 8; ++j) {
      const int k = kc * 32 + quad * 8 + j;
      f[j] = (_Float16)((n16 < 7) ? Wfc[n16 * H_ + k] : 0.0f);
    }
    wfc[kc] = f;
  }

  // ---- init LDS: zero both buffers, write x(0) into buf 0 ----
  for (int i2 = tid; i2 < 2 * 2 * 168; i2 += 512)
    ((_Float16*)abuf)[i2] = (_Float16)0.0f;
  __syncthreads();
  const int xb = (lane < 26) ? (lane / 13) : 0;
  const int xi = (lane < 26) ? (lane - 13 * (lane / 13)) : 0;
  float xreg = 0.0f;
  if (wave == 4 && lane < 26) {
    abuf[0][xb][128 + xi] = (_Float16)x[(size_t)(wgb + xb) * I_ + xi];
    xreg = x[((size_t)1 * B_ + wgb + xb) * I_ + xi];   // x(1), written at t=0
  }
  __syncthreads();

  float c_state = 0.0f;           // lanes 0..31: cell (row=quad, j=16w+n16)
  const bool aload = (n16 == 0) || (n16 == 4);
  const int  arow  = n16 >> 2;    // batch row for A-frag load lanes

  half8 af[5];
  {
    half8 z;
    #pragma unroll
    for (int j = 0; j < 8; ++j) z[j] = (_Float16)0.0f;
    #pragma unroll
    for (int kc = 0; kc < 5; ++kc) af[kc] = z;
  }

  for (int t = 0; t <= T_; ++t) {
    // depth-2 x prefetch: issue load of x(t+2); xreg holds x(t+1)
    float xnew = 0.0f;
    if (wave == 4 && lane < 26 && (t + 2) < T_)
      xnew = x[((size_t)(t + 2) * B_ + wgb + xb) * I_ + xi];

    // A fragments from current buffer (rows 0 and 4 real, rest zero)
    if (aload) {
      #pragma unroll
      for (int kc = 0; kc < 5; ++kc)
        af[kc] = *(const half8*)&abuf[t & 1][arow][kc * 32 + quad * 8];
    }

    // fc logits for h(t-1) (wave 0): k chunks 0..3 only
    float4_ accf;
    #pragma unroll
    for (int r = 0; r < 4; ++r) accf[r] = biasfc;
    if (wave == 0) {
      #pragma unroll
      for (int kc = 0; kc < 4; ++kc)
        accf = __builtin_amdgcn_mfma_f32_16x16x32_f16(af[kc], wfc[kc], accf, 0, 0, 0);
    }

    if (t < T_) {
      // gates = [h|x] @ [Whh|Wih]^T + bias
      float4_ acc[4];
      #pragma unroll
      for (int ti = 0; ti < 4; ++ti) {
        #pragma unroll
        for (int r = 0; r < 4; ++r) acc[ti][r] = biasv[ti];
      }
      #pragma unroll
      for (int kc = 0; kc < 5; ++kc) {
        #pragma unroll
        for (int ti = 0; ti < 4; ++ti)
          acc[ti] = __builtin_amdgcn_mfma_f32_16x16x32_f16(af[kc], wfrag[ti][kc], acc[ti], 0, 0, 0);
      }
      // cell update straight from accumulators (lanes 0..31, reg 0)
      if (lane < 32) {
        const float iv = sigmoid_f(acc[0][0]);
        const float fv = sigmoid_f(acc[1][0]);
        const float gv = tanh_f(acc[2][0]);
        const float ov = sigmoid_f(acc[3][0]);
        c_state = fv * c_state + iv * gv;
        const float hv = ov * tanh_f(c_state);
        abuf[(t + 1) & 1][quad][16 * wave + n16] = (_Float16)hv;
      }
    }

    // softmax of logits (rows 0,1 in lanes 0..6 / 16..22 of accf[0])
    if (t >= 1 && wave == 0) {
      const bool valid = (n16 < 7) && (lane < 32);
      const float v = accf[0];
      float vm = valid ? v : -3.0e38f;
      vm = fmaxf(vm, __shfl_xor(vm, 1, 8));
      vm = fmaxf(vm, __shfl_xor(vm, 2, 8));
      vm = fmaxf(vm, __shfl_xor(vm, 4, 8));
      const float e = valid ? fast_exp2(LOG2E * (v - vm)) : 0.0f;
      float s = e;
      s += __shfl_xor(s, 1, 8);
      s += __shfl_xor(s, 2, 8);
      s += __shfl_xor(s, 4, 8);
      if (valid)
        out[((size_t)(t - 1) * B_ + wgb + quad) * 7 + n16] = e * fast_rcp(s);
    }

    // stage x(t+1) into the next buffer
    if (wave == 4 && lane < 26 && (t + 1) < T_) {
      abuf[(t + 1) & 1][xb][128 + xi] = (_Float16)xreg;
      xreg = xnew;
    }

    wg_barrier_lds();   // lgkm-only: no vmcnt drain
  }
}

extern "C" void kernel_launch(void* const* d_in, const int* in_sizes, int n_in,
                              void* d_out, int out_size, void* d_ws, size_t ws_size,
                              hipStream_t stream) {
  (void)in_sizes; (void)n_in; (void)out_size; (void)d_ws; (void)ws_size;
  const float* x   = (const float*)d_in[0];
  const float* Wih = (const float*)d_in[1];
  const float* Whh = (const float*)d_in[2];
  const float* bih = (const float*)d_in[3];
  const float* bhh = (const float*)d_in[4];
  const float* Wfc = (const float*)d_in[5];
  const float* bfc = (const float*)d_in[6];
  hipLaunchKernelGGL(lstm_fused, dim3(256), dim3(512), 0, stream,
                     x, Wih, Whh, bih, bhh, Wfc, bfc, (float*)d_out);
}